// Round 1
// baseline (183.134 us; speedup 1.0000x reference)
//
#include <hip/hip_runtime.h>
#include <math.h>

#define D 128
#define C 64
#define P1_THREADS 1024  // 16 waves/CU at 1 block/CU (VGPR<=128 forced by bounds)
#define P1_GRID 256      // nb=256 partial buffers: halves partial traffic vs 512

// Monotone float->uint key: preserves order under unsigned max.
// key(x) > 0 for any finite float x, so 0 == "empty".
__device__ __forceinline__ unsigned f2key(float f) {
  unsigned u = __float_as_uint(f);
  return (u & 0x80000000u) ? ~u : (u | 0x80000000u);
}
__device__ __forceinline__ float key2f(unsigned k) {
  unsigned u = (k & 0x80000000u) ? (k & 0x7fffffffu) : ~k;
  return __uint_as_float(u);
}

// ---- Phase 1: per-block segment max via fire-and-forget LDS atomicMax ----
// LDS swizzle: idx = core*128 + (d%4)*32 + d/4 -> ds_max is 2-way/bank (free).
// R4: global atomics into 512 lines cost +19us; R6: cooperative fusion cost
// +131us -- keep partial-buffer shape.
// R7 (this round): 2-deep SW pipeline (loads of tile t+1 issue before atomics
// of tile t) + branchless tail via row-clamp (max is idempotent: duplicated
// boundary row re-maxes the same value -> correct, no divergence).

__device__ __forceinline__ void p1_load(const int* __restrict__ assign,
                                        const float* __restrict__ qe, int Q,
                                        int base, int lane, int r,
                                        float4* v, int* a) {
#pragma unroll
  for (int i = 0; i < 4; ++i) {
    int row = base + i * 32 + r;
    row = row < Q ? row : Q - 1;  // idempotent-max tail clamp
    v[i] = *(const float4*)&qe[(size_t)row * D + lane * 4];
    a[i] = assign[row] * D + lane;
  }
}

__device__ __forceinline__ void p1_atom(unsigned* buf, const float4* v,
                                        const int* a) {
#pragma unroll
  for (int i = 0; i < 4; ++i) {
    atomicMax(&buf[a[i] +  0], f2key(v[i].x));
    atomicMax(&buf[a[i] + 32], f2key(v[i].y));
    atomicMax(&buf[a[i] + 64], f2key(v[i].z));
    atomicMax(&buf[a[i] + 96], f2key(v[i].w));
  }
}

__global__ __launch_bounds__(P1_THREADS) void p1_segmax(
    const int* __restrict__ assign, const float* __restrict__ qe,
    unsigned* __restrict__ part, int Q, int niter) {
  __shared__ unsigned buf[C * D];  // 32 KB
  int tid = threadIdx.x;
  for (int i = tid; i < C * D; i += P1_THREADS) buf[i] = 0u;

  int lane = tid & 31;  // dim quad: dims [lane*4, lane*4+4)
  int r = tid >> 5;     // row slot 0..31
  int stride = gridDim.x;

  int it = blockIdx.x;
  bool any = it < niter;
  float4 v0[4];
  int a0[4];
  // Prologue loads issue before the barrier: overlap LDS init with HBM latency.
  if (any) p1_load(assign, qe, Q, it * 128, lane, r, v0, a0);
  __syncthreads();

  while (any) {
    int nx = it + stride;
    bool more = nx < niter;
    float4 v1[4];
    int a1[4];
    if (more) p1_load(assign, qe, Q, nx * 128, lane, r, v1, a1);  // prefetch
    p1_atom(buf, v0, a0);  // consume current while next tile is in flight
    if (more) {
#pragma unroll
      for (int i = 0; i < 4; ++i) { v0[i] = v1[i]; a0[i] = a1[i]; }
    }
    it = nx;
    any = more;
  }
  __syncthreads();

  // Un-swizzle on write-out (coalesced global stores).
  unsigned* outp = part + (size_t)blockIdx.x * (C * D);
  for (int i = tid; i < C * D; i += P1_THREADS) {
    int d = i & 127;
    outp[i] = buf[(i & ~127) + (d & 3) * 32 + (d >> 2)];
  }
}

// ---- Phase 2: reduce nb partial key-buffers -> core_embs floats ----
// R7: one core per block (64 blocks x 256 threads), uint4 loads: each
// half-wave reads 512B contiguous (was 128B scalar at 32KB stride).
__global__ __launch_bounds__(256) void p2_merge(
    const unsigned* __restrict__ part, const float* __restrict__ padding,
    float* __restrict__ core_embs, int nb) {
  __shared__ uint4 red[8][32];
  int tid = threadIdx.x;
  int q = tid & 31;    // uint4 column: dims [q*4, q*4+4)
  int rdr = tid >> 5;  // 0..7 readers
  int c = blockIdx.x;
  size_t base = (size_t)c * D + q * 4;

  uint4 m = make_uint4(0u, 0u, 0u, 0u);
#pragma unroll 8
  for (int br = rdr; br < nb; br += 8) {
    uint4 x = *(const uint4*)(part + (size_t)br * (C * D) + base);
    m.x = max(m.x, x.x);
    m.y = max(m.y, x.y);
    m.z = max(m.z, x.z);
    m.w = max(m.w, x.w);
  }
  red[rdr][q] = m;
  __syncthreads();
  if (tid < 32) {
    uint4 k = red[0][tid];
#pragma unroll
    for (int j = 1; j < 8; ++j) {
      uint4 x = red[j][tid];
      k.x = max(k.x, x.x);
      k.y = max(k.y, x.y);
      k.z = max(k.z, x.z);
      k.w = max(k.w, x.w);
    }
    float4 o;
    o.x = k.x ? key2f(k.x) : padding[tid * 4 + 0];
    o.y = k.y ? key2f(k.y) : padding[tid * 4 + 1];
    o.z = k.z ? key2f(k.z) : padding[tid * 4 + 2];
    o.w = k.w ? key2f(k.w) : padding[tid * 4 + 3];
    *(float4*)(core_embs + (size_t)c * D + tid * 4) = o;
  }
}

// ---- Phase 3 (fused): out = relu(CE @ Wself + (con @ CE) @ Wmsg + b) ----
// R7: no 32KB CE staging (CE is L2/L3-hot, 32KB total); con is 0/1 and
// block-uniform -> uniform branch skips ~70% of message-row loads; 256
// threads = 4 waves with 2-way split-k, halving the dependent-load chain.
__global__ __launch_bounds__(256) void p3_fused(
    const float* __restrict__ core_embs, const float* __restrict__ con,
    const float* __restrict__ Wself, const float* __restrict__ Wmsg,
    const float* __restrict__ b, float* __restrict__ out) {
  __shared__ float crow[C];
  __shared__ float CEc[D];
  __shared__ float Mp[2][D];  // Mrow halves: j<32 | j>=32
  __shared__ float Ap[2][D];  // acc halves:  k<64 | k>=64
  int tid = threadIdx.x;
  int c = blockIdx.x;
  int t = tid & (D - 1);
  int h = tid >> 7;  // 0 or 1 (waves don't straddle h)

  if (tid < C) crow[tid] = con[c * C + tid];
  if (tid < D) CEc[tid] = core_embs[(size_t)c * D + tid];
  __syncthreads();

  // Mrow[t] = sum_j con[c][j] * CE[j][t], split over j-halves.
  float m = 0.f;
  int j0 = h * 32;
#pragma unroll
  for (int jj = 0; jj < 32; ++jj) {
    int j = j0 + jj;
    if (crow[j] != 0.f)  // uniform across wave: scalar skip (~70% of rows)
      m += core_embs[(size_t)j * D + t];
  }
  Mp[h][t] = m;
  __syncthreads();

  float acc = (h == 0) ? b[t] : 0.f;
  int k0 = h * 64;
#pragma unroll 8
  for (int kk = 0; kk < 64; ++kk) {
    int k = k0 + kk;
    float mr = Mp[0][k] + Mp[1][k];  // LDS broadcast (free)
    acc = fmaf(CEc[k], Wself[(size_t)k * D + t], acc);
    acc = fmaf(mr, Wmsg[(size_t)k * D + t], acc);
  }
  Ap[h][t] = acc;
  __syncthreads();
  if (h == 0) out[(size_t)c * D + t] = fmaxf(Ap[0][t] + Ap[1][t], 0.f);
}

extern "C" void kernel_launch(void* const* d_in, const int* in_sizes, int n_in,
                              void* d_out, int out_size, void* d_ws, size_t ws_size,
                              hipStream_t stream) {
  const int* assign    = (const int*)d_in[0];
  const float* qe      = (const float*)d_in[1];
  const float* padding = (const float*)d_in[2];
  const float* con     = (const float*)d_in[3];
  const float* Wself   = (const float*)d_in[4];
  const float* Wmsg    = (const float*)d_in[5];
  const float* b       = (const float*)d_in[6];
  float* out = (float*)d_out;
  int Q = in_sizes[0];

  const size_t slot = (size_t)C * D;  // 8192 elems = 32 KB
  size_t avail = ws_size / 4;
  long nb_max = (long)((avail > slot ? avail - slot : slot) / slot);
  int nb = (int)(nb_max < P1_GRID ? nb_max : P1_GRID);
  if (nb < 1) nb = 1;

  unsigned* part   = (unsigned*)d_ws;
  float* core_embs = (float*)((unsigned*)d_ws + (size_t)nb * slot);

  int niter = (Q + 127) / 128;

  hipLaunchKernelGGL(p1_segmax, dim3(nb), dim3(P1_THREADS), 0, stream,
                     assign, qe, part, Q, niter);
  hipLaunchKernelGGL(p2_merge, dim3(C), dim3(256), 0, stream,
                     part, padding, core_embs, nb);
  hipLaunchKernelGGL(p3_fused, dim3(C), dim3(256), 0, stream,
                     core_embs, con, Wself, Wmsg, b, out);
}